// Round 4
// baseline (276.065 us; speedup 1.0000x reference)
//
#include <hip/hip_runtime.h>
#include <math.h>

#define BATCH 8
#define CDIM 256
#define NDIM 2048
#define SCALE 0.0625f  // 1/sqrt(256)

typedef _Float16 half8v __attribute__((ext_vector_type(8)));
typedef _Float16 half4v __attribute__((ext_vector_type(4)));
typedef float floatx4 __attribute__((ext_vector_type(4)));
typedef float floatx2 __attribute__((ext_vector_type(2)));

// workspace offsets (bytes)
#define WS_SPART 0                      // 8*16*2048 floats = 1 MB
#define WS_KT    1048576                // 8.4 MB
#define WS_QT    9437184                // 8.4 MB
#define WS_VT    17825792               // 8.4 MB (fp16 V, plain [b][c][i])
#define WS_EHT   26214400               // 67 MB
// total ws use: ~89 MB

// Bs/As chunk swizzle: per-row rotation, conflict-free for staging-store,
// MFMA fragment reads, and the W transpose gather.
#define BSWZ(c, j) (((((c) + (j) + ((j) >> 3)) & 7)) << 3)

// ---------------------------------------------------------------------------
// prep: K,Q -> fp16 transposed+tiled [b][ib(16)][cb(8)][i(128)][c(32)];
// V -> fp16 cast, layout unchanged [b][c][i].
// ---------------------------------------------------------------------------
__global__ __launch_bounds__(256) void prep_kernel(const float* __restrict__ Q,
                                                   const float* __restrict__ K,
                                                   const float* __restrict__ V,
                                                   _Float16* __restrict__ Kt,
                                                   _Float16* __restrict__ Qt,
                                                   _Float16* __restrict__ Vt) {
    if (blockIdx.y == 2) {
        const int t = threadIdx.x;
#pragma unroll
        for (int u = 0; u < 4; ++u) {
            const size_t idx = (size_t)blockIdx.x * 4096 + (u * 256 + t) * 4;
            float4 f = *(const float4*)&V[idx];
            half4v h = {(_Float16)f.x, (_Float16)f.y, (_Float16)f.z, (_Float16)f.w};
            *(half4v*)&Vt[idx] = h;
        }
        return;
    }
    const int g = blockIdx.x * 256 + threadIdx.x;
    const float* src = (blockIdx.y == 0) ? K : Q;
    _Float16* dst = (blockIdx.y == 0) ? Kt : Qt;
    const int b = g >> 15, r = g & 32767;
    const int iq = r & 511, cq = r >> 9;  // i-quad (512), c-quad (64)
    const float* p = src + (size_t)b * CDIM * NDIM + (size_t)(cq * 4) * NDIM + iq * 4;
    float fr[4][4];
    *(float4*)fr[0] = *(const float4*)(p);
    *(float4*)fr[1] = *(const float4*)(p + NDIM);
    *(float4*)fr[2] = *(const float4*)(p + 2 * NDIM);
    *(float4*)fr[3] = *(const float4*)(p + 3 * NDIM);
    const int cb = cq >> 3, cc0 = (cq & 7) * 4;
#pragma unroll
    for (int ii = 0; ii < 4; ++ii) {
        const int i = iq * 4 + ii;
        const int ib = i >> 7, il = i & 127;
        half4v h = {(_Float16)fr[0][ii], (_Float16)fr[1][ii],
                    (_Float16)fr[2][ii], (_Float16)fr[3][ii]};
        *(half4v*)&dst[((((size_t)(b * 16 + ib) * 8 + cb) * 128 + il) * 32) + cc0] = h;
    }
}

// ---------------------------------------------------------------------------
// GEMM1: E = exp(SCALE * K^T Q). LDS double-buffer, one sync per K-step,
// register prefetch. NEW: XCD-rectangle block decode (each XCD owns a
// 4-ib2 x 8-jb2 rectangle per batch -> Kt fetch 16 strips/XCD -> 4) and
// nontemporal EhT stores (write-once stream, keep L2 for Kt/Qt reuse).
// ---------------------------------------------------------------------------
#define G1_LOAD(CB, A0, A1, B0, B1)                          \
    do {                                                     \
        A0 = *(const half8v*)(Ab + (CB) * 4096 + ci0 * 8);   \
        A1 = *(const half8v*)(Ab + (CB) * 4096 + ci1 * 8);   \
        B0 = *(const half8v*)(Bb + (CB) * 4096 + ci0 * 8);   \
        B1 = *(const half8v*)(Bb + (CB) * 4096 + ci1 * 8);   \
    } while (0)

#define G1_STAGE(ALp, BLp, A0, A1, B0, B1)    \
    do {                                      \
        *(half8v*)&(ALp)[oA0] = A0;           \
        *(half8v*)&(ALp)[oA1] = A1;           \
        *(half8v*)&(BLp)[oA0] = B0;           \
        *(half8v*)&(BLp)[oA1] = B1;           \
    } while (0)

#define G1_MFMA(ALp, BLp)                                                          \
    do {                                                                           \
        half8v af[4], bf[4];                                                       \
        _Pragma("unroll") for (int m = 0; m < 4; ++m)                              \
            af[m] = *(const half8v*)&(ALp)[(wy * 64 + m * 16 + lr) * 40 + quad * 8]; \
        _Pragma("unroll") for (int n = 0; n < 4; ++n)                              \
            bf[n] = *(const half8v*)&(BLp)[(wx * 64 + n * 16 + lr) * 40 + quad * 8]; \
        _Pragma("unroll") for (int m = 0; m < 4; ++m)                              \
            _Pragma("unroll") for (int n = 0; n < 4; ++n)                          \
                acc[m][n] = __builtin_amdgcn_mfma_f32_16x16x32_f16(                \
                    af[m], bf[n], acc[m][n], 0, 0, 0);                             \
    } while (0)

__global__ __launch_bounds__(256) void gemm1_kernel(const _Float16* __restrict__ Kt,
                                                    const _Float16* __restrict__ Qt,
                                                    _Float16* __restrict__ EhT,
                                                    float* __restrict__ Spart) {
    __shared__ _Float16 Al[2][128 * 40];
    __shared__ _Float16 Bl[2][128 * 40];
    __shared__ _Float16 LT[128 * 128];
    __shared__ float Sl[2][128];
    // XCD-rectangle decode: XCD = bid%8 owns ib2 in [4*(xcd&3),+4),
    // jb2 in [8*(xcd>>2),+8) for batch bid>>8. L2 working set/XCD/batch:
    // 4 Kt strips + 8 Qt strips = 768 KB.
    const int bid = blockIdx.x;
    const int b = bid >> 8, r = bid & 255;
    const int xcd = r & 7, q = r >> 3;
    const int ib2 = (xcd & 3) * 4 + (q & 3);
    const int jb2 = (xcd >> 2) * 8 + (q >> 2);
    const _Float16* Ab = Kt + (size_t)(b * 16 + ib2) * 8 * 4096;
    const _Float16* Bb = Qt + (size_t)(b * 16 + jb2) * 8 * 4096;
    const int t = threadIdx.x, wave = t >> 6, lane = t & 63;
    const int wy = wave >> 1, wx = wave & 1, quad = lane >> 4, lr = lane & 15;
    floatx4 acc[4][4] = {};
    const int ci0 = t * 2, ci1 = t * 2 + 1;
    const int oA0 = (ci0 >> 2) * 40 + (ci0 & 3) * 8;
    const int oA1 = (ci1 >> 2) * 40 + (ci1 & 3) * 8;

    half8v a00, a01, b00, b01, a10, a11, b10, b11;
    G1_LOAD(0, a00, a01, b00, b01);
    G1_STAGE(Al[0], Bl[0], a00, a01, b00, b01);
    G1_LOAD(1, a10, a11, b10, b11);
    __syncthreads();
#pragma unroll
    for (int cbp = 0; cbp < 4; ++cbp) {
        const int cbE = cbp * 2, cbO = cbp * 2 + 1;
        G1_STAGE(Al[1], Bl[1], a10, a11, b10, b11);
        G1_LOAD((cbE + 2) & 7, a00, a01, b00, b01);
        G1_MFMA(Al[0], Bl[0]);
        __syncthreads();
        G1_STAGE(Al[0], Bl[0], a00, a01, b00, b01);
        G1_LOAD((cbO + 2) & 7, a10, a11, b10, b11);
        G1_MFMA(Al[1], Bl[1]);
        __syncthreads();
    }

    // epilogue: exp -> LDS transpose (chunk-swizzled) + column partial sums
    float psum[4] = {0.f, 0.f, 0.f, 0.f};
#pragma unroll
    for (int m = 0; m < 4; ++m) {
#pragma unroll
        for (int n = 0; n < 4; ++n) {
            const int j_loc = wx * 64 + n * 16 + lr;
#pragma unroll
            for (int r2 = 0; r2 < 4; ++r2) {
                const int i_loc = wy * 64 + m * 16 + quad * 4 + r2;
                float e = __expf(acc[m][n][r2] * SCALE);
                psum[n] += e;
                LT[j_loc * 128 + (((i_loc >> 3) ^ (j_loc & 7)) << 3) + (i_loc & 7)] = (_Float16)e;
            }
        }
    }
#pragma unroll
    for (int n = 0; n < 4; ++n) {
        float s = psum[n];
        s += __shfl_xor(s, 16, 64);
        s += __shfl_xor(s, 32, 64);
        if (quad == 0) Sl[wy][wx * 64 + n * 16 + lr] = s;
    }
    __syncthreads();
    if (t < 128)
        Spart[((size_t)(b * 16 + ib2)) * 2048 + jb2 * 128 + t] = Sl[0][t] + Sl[1][t];

    const int jh = wave >> 1, ih = wave & 1;
    _Float16* dst = EhT + ((size_t)((b * 32 + jb2 * 2 + jh) * 32) + ib2 * 2 + ih) * 4096;
#pragma unroll
    for (int cc = 0; cc < 8; ++cc) {
        const int j = jh * 64 + cc * 8 + (lane >> 3);
        half8v h = *(const half8v*)&LT[j * 128 + (((ih * 8 + (lane & 7)) ^ (lane >> 3)) << 3)];
        __builtin_nontemporal_store(h, (half8v*)&dst[cc * 512 + lane * 8]);
    }
}

// ---------------------------------------------------------------------------
// GEMM2 (fused): out[b,c,j] = invS[j] * sum_i V[c,i] * E[i,j]  AND
// W[b,i,j] = E[i,j] * invS[j]. Block 128c x 128j, 512 threads, LDS dbuf,
// one sync per K-step. NEW: XCD decode b = bid&7 (each XCD touches only
// Vt[b] = 1 MB instead of all 8.4 MB) and nontemporal W/Out stores
// (134+17 MB write-once streams no longer evict Vt/EhT from L2).
// ---------------------------------------------------------------------------
#define G2_LOAD(IT, AV, BV)                                                        \
    do {                                                                           \
        _Pragma("unroll") for (int u = 0; u < 2; ++u) {                            \
            const int f = u * 512 + t;                                             \
            const int c = f >> 3, i8 = f & 7;                                      \
            AV[u] = *(const half8v*)&Vtb[(size_t)c * 2048 + (IT) * 64 + i8 * 8];   \
        }                                                                          \
        _Pragma("unroll") for (int u = 0; u < 2; ++u) {                            \
            const int f = u * 512 + t;                                             \
            const int jl = f >> 3, c8 = f & 7;                                     \
            const int jbv = jb2 * 2 + (jl >> 6);                                   \
            BV[u] = *(const half8v*)&EhT[((size_t)((b * 32 + jbv) * 32) + (IT)) *  \
                                             4096 +                                \
                                         (jl & 63) * 64 + c8 * 8];                 \
        }                                                                          \
    } while (0)

#define G2_STAGE(ASp, BSp, AV, BV)                                \
    do {                                                          \
        _Pragma("unroll") for (int u = 0; u < 2; ++u) {           \
            const int f = u * 512 + t;                            \
            const int c = f >> 3, i8 = f & 7;                     \
            *(half8v*)&(ASp)[c * 72 + BSWZ(i8, c)] = AV[u];       \
        }                                                         \
        _Pragma("unroll") for (int u = 0; u < 2; ++u) {           \
            const int f = u * 512 + t;                            \
            const int jl = f >> 3, c8 = f & 7;                    \
            *(half8v*)&(BSp)[jl * 72 + BSWZ(c8, jl)] = BV[u];     \
        }                                                         \
    } while (0)

#define G2_MFMA(ASp, BSp)                                                          \
    do {                                                                           \
        _Pragma("unroll") for (int ks = 0; ks < 2; ++ks) {                         \
            half8v af[4], bf[2];                                                   \
            _Pragma("unroll") for (int m = 0; m < 4; ++m) {                        \
                const int row = wy * 64 + m * 16 + lr;                             \
                af[m] = *(const half8v*)&(ASp)[row * 72 + BSWZ(ks * 4 + quad, row)]; \
            }                                                                      \
            _Pragma("unroll") for (int n = 0; n < 2; ++n) {                        \
                const int row = wx * 32 + n * 16 + lr;                             \
                bf[n] = *(const half8v*)&(BSp)[row * 72 + BSWZ(ks * 4 + quad, row)]; \
            }                                                                      \
            _Pragma("unroll") for (int m = 0; m < 4; ++m)                          \
                _Pragma("unroll") for (int n = 0; n < 2; ++n)                      \
                    acc[m][n] = __builtin_amdgcn_mfma_f32_16x16x32_f16(            \
                        af[m], bf[n], acc[m][n], 0, 0, 0);                         \
        }                                                                          \
    } while (0)

#define G2_WDUTY(BSp, IT)                                                          \
    do {                                                                           \
        half8v hv0 = *(const half8v*)&(BSp)[j0 * 72 + BSWZ(ti, j0)];               \
        half8v hv1 = *(const half8v*)&(BSp)[(j0 + 1) * 72 + BSWZ(ti, j0 + 1)];     \
        float* Wr = Wb + (size_t)((IT) * 64 + ti * 8) * 2048;                      \
        _Pragma("unroll") for (int e = 0; e < 8; ++e) {                            \
            floatx2 o = {(float)hv0[e] * iv0, (float)hv1[e] * iv1};                \
            __builtin_nontemporal_store(o, (floatx2*)&Wr[(size_t)e * 2048 + j0]);  \
        }                                                                          \
    } while (0)

__global__ __launch_bounds__(512) void gemm2_kernel(const _Float16* __restrict__ Vt,
                                                    const _Float16* __restrict__ EhT,
                                                    const float* __restrict__ Spart,
                                                    float* __restrict__ W,
                                                    float* __restrict__ Out) {
    __shared__ _Float16 As[2][128 * 72];
    __shared__ _Float16 Bs[2][128 * 72];
    __shared__ float invSl[128];
    // XCD decode: XCD = bid%8 = b. Each XCD reads only Vt[b] (1 MB) +
    // EhT[b] (strips shared by concurrent cc2 siblings on the same XCD).
    const int bid = blockIdx.x;
    const int b = bid & 7, rr = bid >> 3;   // rr 0..31
    const int jb2 = rr & 15, cc2 = rr >> 4;
    const int t = threadIdx.x, wave = t >> 6, lane = t & 63;
    const int wy = wave >> 2, wx = wave & 3, quad = lane >> 4, lr = lane & 15;
    const _Float16* Vtb = Vt + ((size_t)(b * 256 + cc2 * 128)) * 2048;
    floatx4 acc[4][2] = {};

    if (t < 128) {
        float s = 0.f;
#pragma unroll
        for (int p = 0; p < 16; ++p)
            s += Spart[((size_t)(b * 16 + p)) * 2048 + jb2 * 128 + t];
        invSl[t] = 1.0f / s;
    }

    // W-path thread mapping: 2 consecutive j x 8 consecutive i per thread
    const int j0 = (t & 63) * 2, ti = t >> 6;
    float* Wb = W + ((size_t)b * 2048) * 2048 + jb2 * 128;
    const bool dutyE = (cc2 == 0), dutyO = (cc2 == 1);

    half8v av0[2], bv0[2], av1[2], bv1[2];
    G2_LOAD(0, av0, bv0);
    G2_STAGE(As[0], Bs[0], av0, bv0);
    G2_LOAD(1, av1, bv1);
    __syncthreads();
    const float iv0 = invSl[j0], iv1 = invSl[j0 + 1];

    for (int ip = 0; ip < 16; ++ip) {
        const int itE = ip * 2, itO = ip * 2 + 1;
        G2_STAGE(As[1], Bs[1], av1, bv1);
        G2_LOAD((itE + 2) & 31, av0, bv0);
        G2_MFMA(As[0], Bs[0]);
        if (dutyE) G2_WDUTY(Bs[0], itE);
        __syncthreads();
        G2_STAGE(As[0], Bs[0], av0, bv0);
        G2_LOAD((itO + 2) & 31, av1, bv1);
        G2_MFMA(As[1], Bs[1]);
        if (dutyO) G2_WDUTY(Bs[1], itO);
        __syncthreads();
    }

    float* Ob = Out + ((size_t)(b * 256 + cc2 * 128)) * 2048 + jb2 * 128;
    float iv[2];
#pragma unroll
    for (int n = 0; n < 2; ++n)
        iv[n] = invSl[wx * 32 + n * 16 + lr];
#pragma unroll
    for (int m = 0; m < 4; ++m) {
        const int c0r = wy * 64 + m * 16 + quad * 4;
#pragma unroll
        for (int n = 0; n < 2; ++n) {
            const int j = wx * 32 + n * 16 + lr;
#pragma unroll
            for (int r2 = 0; r2 < 4; ++r2)
                __builtin_nontemporal_store(acc[m][n][r2] * iv[n],
                                            &Ob[(size_t)(c0r + r2) * 2048 + j]);
        }
    }
}

extern "C" void kernel_launch(void* const* d_in, const int* in_sizes, int n_in,
                              void* d_out, int out_size, void* d_ws, size_t ws_size,
                              hipStream_t stream) {
    const float* q = (const float*)d_in[0];
    const float* k = (const float*)d_in[1];
    const float* v = (const float*)d_in[2];
    float* out = (float*)d_out;
    float* w = out + (size_t)BATCH * CDIM * NDIM;  // weights region

    char* ws = (char*)d_ws;
    float* Spart = (float*)(ws + WS_SPART);
    _Float16* Kt = (_Float16*)(ws + WS_KT);
    _Float16* Qt = (_Float16*)(ws + WS_QT);
    _Float16* Vt = (_Float16*)(ws + WS_VT);
    _Float16* EhT = (_Float16*)(ws + WS_EHT);

    prep_kernel<<<dim3(1024, 3), 256, 0, stream>>>(q, k, v, Kt, Qt, Vt);
    gemm1_kernel<<<2048, 256, 0, stream>>>(Kt, Qt, EhT, Spart);
    gemm2_kernel<<<256, 512, 0, stream>>>(Vt, EhT, Spart, w, out);
}

// Round 5
// 250.372 us; speedup vs baseline: 1.1026x; 1.1026x over previous
//
#include <hip/hip_runtime.h>
#include <math.h>

#define BATCH 8
#define CDIM 256
#define NDIM 2048
#define SCALE 0.0625f  // 1/sqrt(256)

typedef _Float16 half8v __attribute__((ext_vector_type(8)));
typedef _Float16 half4v __attribute__((ext_vector_type(4)));
typedef float floatx4 __attribute__((ext_vector_type(4)));
typedef float floatx2 __attribute__((ext_vector_type(2)));

// workspace offsets (bytes)
#define WS_SPART 0                      // 8*16*2048 floats = 1 MB
#define WS_KT    1048576                // 8.4 MB
#define WS_QT    9437184                // 8.4 MB
#define WS_VT    17825792               // 8.4 MB (fp16 V, plain [b][c][i])
#define WS_EHT   26214400               // 67 MB
// total ws use: ~89 MB

// Bs/As chunk swizzle: per-row rotation, conflict-free for staging-store,
// MFMA fragment reads, and the W transpose gather.
#define BSWZ(c, j) (((((c) + (j) + ((j) >> 3)) & 7)) << 3)

// T4 barrier: drain LDS ops only; in-flight global loads CROSS the barrier
// (__syncthreads would emit s_waitcnt vmcnt(0) and kill the prefetch).
#define BAR_LGKM() asm volatile("s_waitcnt lgkmcnt(0)\n\ts_barrier" ::: "memory")

// ---------------------------------------------------------------------------
// prep: K,Q -> fp16 transposed+tiled [b][ib(16)][cb(8)][i(128)][c(32)];
// V -> fp16 cast, layout unchanged [b][c][i].
// ---------------------------------------------------------------------------
__global__ __launch_bounds__(256) void prep_kernel(const float* __restrict__ Q,
                                                   const float* __restrict__ K,
                                                   const float* __restrict__ V,
                                                   _Float16* __restrict__ Kt,
                                                   _Float16* __restrict__ Qt,
                                                   _Float16* __restrict__ Vt) {
    if (blockIdx.y == 2) {
        const int t = threadIdx.x;
#pragma unroll
        for (int u = 0; u < 4; ++u) {
            const size_t idx = (size_t)blockIdx.x * 4096 + (u * 256 + t) * 4;
            float4 f = *(const float4*)&V[idx];
            half4v h = {(_Float16)f.x, (_Float16)f.y, (_Float16)f.z, (_Float16)f.w};
            *(half4v*)&Vt[idx] = h;
        }
        return;
    }
    const int g = blockIdx.x * 256 + threadIdx.x;
    const float* src = (blockIdx.y == 0) ? K : Q;
    _Float16* dst = (blockIdx.y == 0) ? Kt : Qt;
    const int b = g >> 15, r = g & 32767;
    const int iq = r & 511, cq = r >> 9;  // i-quad (512), c-quad (64)
    const float* p = src + (size_t)b * CDIM * NDIM + (size_t)(cq * 4) * NDIM + iq * 4;
    float fr[4][4];
    *(float4*)fr[0] = *(const float4*)(p);
    *(float4*)fr[1] = *(const float4*)(p + NDIM);
    *(float4*)fr[2] = *(const float4*)(p + 2 * NDIM);
    *(float4*)fr[3] = *(const float4*)(p + 3 * NDIM);
    const int cb = cq >> 3, cc0 = (cq & 7) * 4;
#pragma unroll
    for (int ii = 0; ii < 4; ++ii) {
        const int i = iq * 4 + ii;
        const int ib = i >> 7, il = i & 127;
        half4v h = {(_Float16)fr[0][ii], (_Float16)fr[1][ii],
                    (_Float16)fr[2][ii], (_Float16)fr[3][ii]};
        *(half4v*)&dst[((((size_t)(b * 16 + ib) * 8 + cb) * 128 + il) * 32) + cc0] = h;
    }
}

// ---------------------------------------------------------------------------
// GEMM1: E = exp(SCALE * K^T Q). LDS double-buffer, one lgkm-only barrier
// per K-step (T4: prefetch loads stay in flight across it), register
// prefetch 2 steps ahead, setprio around MFMA (T5). XCD-rectangle decode.
// EhT stores are PLAIN (L3-resident for gemm2 reads — NT was a regression).
// ---------------------------------------------------------------------------
#define G1_LOAD(CB, A0, A1, B0, B1)                          \
    do {                                                     \
        A0 = *(const half8v*)(Ab + (CB) * 4096 + ci0 * 8);   \
        A1 = *(const half8v*)(Ab + (CB) * 4096 + ci1 * 8);   \
        B0 = *(const half8v*)(Bb + (CB) * 4096 + ci0 * 8);   \
        B1 = *(const half8v*)(Bb + (CB) * 4096 + ci1 * 8);   \
    } while (0)

#define G1_STAGE(ALp, BLp, A0, A1, B0, B1)    \
    do {                                      \
        *(half8v*)&(ALp)[oA0] = A0;           \
        *(half8v*)&(ALp)[oA1] = A1;           \
        *(half8v*)&(BLp)[oA0] = B0;           \
        *(half8v*)&(BLp)[oA1] = B1;           \
    } while (0)

#define G1_MFMA(ALp, BLp)                                                          \
    do {                                                                           \
        half8v af[4], bf[4];                                                       \
        _Pragma("unroll") for (int m = 0; m < 4; ++m)                              \
            af[m] = *(const half8v*)&(ALp)[(wy * 64 + m * 16 + lr) * 40 + quad * 8]; \
        _Pragma("unroll") for (int n = 0; n < 4; ++n)                              \
            bf[n] = *(const half8v*)&(BLp)[(wx * 64 + n * 16 + lr) * 40 + quad * 8]; \
        __builtin_amdgcn_s_setprio(1);                                             \
        _Pragma("unroll") for (int m = 0; m < 4; ++m)                              \
            _Pragma("unroll") for (int n = 0; n < 4; ++n)                          \
                acc[m][n] = __builtin_amdgcn_mfma_f32_16x16x32_f16(                \
                    af[m], bf[n], acc[m][n], 0, 0, 0);                             \
        __builtin_amdgcn_s_setprio(0);                                             \
    } while (0)

__global__ __launch_bounds__(256) void gemm1_kernel(const _Float16* __restrict__ Kt,
                                                    const _Float16* __restrict__ Qt,
                                                    _Float16* __restrict__ EhT,
                                                    float* __restrict__ Spart) {
    __shared__ _Float16 Al[2][128 * 40];
    __shared__ _Float16 Bl[2][128 * 40];
    __shared__ _Float16 LT[128 * 128];
    __shared__ float Sl[2][128];
    // XCD-rectangle decode: XCD = bid%8 owns ib2 in [4*(xcd&3),+4),
    // jb2 in [8*(xcd>>2),+8) for batch bid>>8.
    const int bid = blockIdx.x;
    const int b = bid >> 8, r = bid & 255;
    const int xcd = r & 7, q = r >> 3;
    const int ib2 = (xcd & 3) * 4 + (q & 3);
    const int jb2 = (xcd >> 2) * 8 + (q >> 2);
    const _Float16* Ab = Kt + (size_t)(b * 16 + ib2) * 8 * 4096;
    const _Float16* Bb = Qt + (size_t)(b * 16 + jb2) * 8 * 4096;
    const int t = threadIdx.x, wave = t >> 6, lane = t & 63;
    const int wy = wave >> 1, wx = wave & 1, quad = lane >> 4, lr = lane & 15;
    floatx4 acc[4][4] = {};
    const int ci0 = t * 2, ci1 = t * 2 + 1;
    const int oA0 = (ci0 >> 2) * 40 + (ci0 & 3) * 8;
    const int oA1 = (ci1 >> 2) * 40 + (ci1 & 3) * 8;

    half8v a00, a01, b00, b01, a10, a11, b10, b11;
    G1_LOAD(0, a00, a01, b00, b01);
    G1_STAGE(Al[0], Bl[0], a00, a01, b00, b01);
    G1_LOAD(1, a10, a11, b10, b11);
    __syncthreads();
#pragma unroll
    for (int cbp = 0; cbp < 4; ++cbp) {
        const int cbE = cbp * 2, cbO = cbp * 2 + 1;
        // even step: buf0 current, regs set1 hold tile cbE+1
        G1_STAGE(Al[1], Bl[1], a10, a11, b10, b11);
        G1_LOAD((cbE + 2) & 7, a00, a01, b00, b01);
        G1_MFMA(Al[0], Bl[0]);
        BAR_LGKM();
        // odd step: buf1 current, regs set0 hold tile cbO+1
        G1_STAGE(Al[0], Bl[0], a00, a01, b00, b01);
        G1_LOAD((cbO + 2) & 7, a10, a11, b10, b11);
        G1_MFMA(Al[1], Bl[1]);
        BAR_LGKM();
    }

    // epilogue: exp -> LDS transpose (chunk-swizzled) + column partial sums
    float psum[4] = {0.f, 0.f, 0.f, 0.f};
#pragma unroll
    for (int m = 0; m < 4; ++m) {
#pragma unroll
        for (int n = 0; n < 4; ++n) {
            const int j_loc = wx * 64 + n * 16 + lr;
#pragma unroll
            for (int r2 = 0; r2 < 4; ++r2) {
                const int i_loc = wy * 64 + m * 16 + quad * 4 + r2;
                float e = __expf(acc[m][n][r2] * SCALE);
                psum[n] += e;
                LT[j_loc * 128 + (((i_loc >> 3) ^ (j_loc & 7)) << 3) + (i_loc & 7)] = (_Float16)e;
            }
        }
    }
#pragma unroll
    for (int n = 0; n < 4; ++n) {
        float s = psum[n];
        s += __shfl_xor(s, 16, 64);
        s += __shfl_xor(s, 32, 64);
        if (quad == 0) Sl[wy][wx * 64 + n * 16 + lr] = s;
    }
    __syncthreads();
    if (t < 128)
        Spart[((size_t)(b * 16 + ib2)) * 2048 + jb2 * 128 + t] = Sl[0][t] + Sl[1][t];

    const int jh = wave >> 1, ih = wave & 1;
    _Float16* dst = EhT + ((size_t)((b * 32 + jb2 * 2 + jh) * 32) + ib2 * 2 + ih) * 4096;
#pragma unroll
    for (int cc = 0; cc < 8; ++cc) {
        const int j = jh * 64 + cc * 8 + (lane >> 3);
        half8v h = *(const half8v*)&LT[j * 128 + (((ih * 8 + (lane & 7)) ^ (lane >> 3)) << 3)];
        *(half8v*)&dst[cc * 512 + lane * 8] = h;  // plain store: keep L3-resident
    }
}

// ---------------------------------------------------------------------------
// GEMM2 (fused): out[b,c,j] = invS[j] * sum_i V[c,i] * E[i,j]  AND
// W[b,i,j] = E[i,j] * invS[j]. Block 128c x 128j, 512 threads, LDS dbuf,
// one lgkm-only barrier per K-step (T4), setprio (T5). XCD decode b=bid&7.
// NT stores only on W/Out (pure write streams, never re-read).
// ---------------------------------------------------------------------------
#define G2_LOAD(IT, AV, BV)                                                        \
    do {                                                                           \
        _Pragma("unroll") for (int u = 0; u < 2; ++u) {                            \
            const int f = u * 512 + t;                                             \
            const int c = f >> 3, i8 = f & 7;                                      \
            AV[u] = *(const half8v*)&Vtb[(size_t)c * 2048 + (IT) * 64 + i8 * 8];   \
        }                                                                          \
        _Pragma("unroll") for (int u = 0; u < 2; ++u) {                            \
            const int f = u * 512 + t;                                             \
            const int jl = f >> 3, c8 = f & 7;                                     \
            const int jbv = jb2 * 2 + (jl >> 6);                                   \
            BV[u] = *(const half8v*)&EhT[((size_t)((b * 32 + jbv) * 32) + (IT)) *  \
                                             4096 +                                \
                                         (jl & 63) * 64 + c8 * 8];                 \
        }                                                                          \
    } while (0)

#define G2_STAGE(ASp, BSp, AV, BV)                                \
    do {                                                          \
        _Pragma("unroll") for (int u = 0; u < 2; ++u) {           \
            const int f = u * 512 + t;                            \
            const int c = f >> 3, i8 = f & 7;                     \
            *(half8v*)&(ASp)[c * 72 + BSWZ(i8, c)] = AV[u];       \
        }                                                         \
        _Pragma("unroll") for (int u = 0; u < 2; ++u) {           \
            const int f = u * 512 + t;                            \
            const int jl = f >> 3, c8 = f & 7;                    \
            *(half8v*)&(BSp)[jl * 72 + BSWZ(c8, jl)] = BV[u];     \
        }                                                         \
    } while (0)

#define G2_MFMA(ASp, BSp)                                                          \
    do {                                                                           \
        _Pragma("unroll") for (int ks = 0; ks < 2; ++ks) {                         \
            half8v af[4], bf[2];                                                   \
            _Pragma("unroll") for (int m = 0; m < 4; ++m) {                        \
                const int row = wy * 64 + m * 16 + lr;                             \
                af[m] = *(const half8v*)&(ASp)[row * 72 + BSWZ(ks * 4 + quad, row)]; \
            }                                                                      \
            _Pragma("unroll") for (int n = 0; n < 2; ++n) {                        \
                const int row = wx * 32 + n * 16 + lr;                             \
                bf[n] = *(const half8v*)&(BSp)[row * 72 + BSWZ(ks * 4 + quad, row)]; \
            }                                                                      \
            __builtin_amdgcn_s_setprio(1);                                         \
            _Pragma("unroll") for (int m = 0; m < 4; ++m)                          \
                _Pragma("unroll") for (int n = 0; n < 2; ++n)                      \
                    acc[m][n] = __builtin_amdgcn_mfma_f32_16x16x32_f16(            \
                        af[m], bf[n], acc[m][n], 0, 0, 0);                         \
            __builtin_amdgcn_s_setprio(0);                                         \
        }                                                                          \
    } while (0)

#define G2_WDUTY(BSp, IT)                                                          \
    do {                                                                           \
        half8v hv0 = *(const half8v*)&(BSp)[j0 * 72 + BSWZ(ti, j0)];               \
        half8v hv1 = *(const half8v*)&(BSp)[(j0 + 1) * 72 + BSWZ(ti, j0 + 1)];     \
        float* Wr = Wb + (size_t)((IT) * 64 + ti * 8) * 2048;                      \
        _Pragma("unroll") for (int e = 0; e < 8; ++e) {                            \
            floatx2 o = {(float)hv0[e] * iv0, (float)hv1[e] * iv1};                \
            __builtin_nontemporal_store(o, (floatx2*)&Wr[(size_t)e * 2048 + j0]);  \
        }                                                                          \
    } while (0)

__global__ __launch_bounds__(512) void gemm2_kernel(const _Float16* __restrict__ Vt,
                                                    const _Float16* __restrict__ EhT,
                                                    const float* __restrict__ Spart,
                                                    float* __restrict__ W,
                                                    float* __restrict__ Out) {
    __shared__ _Float16 As[2][128 * 72];
    __shared__ _Float16 Bs[2][128 * 72];
    __shared__ float invSl[128];
    // XCD decode: XCD = bid%8 = b. Each XCD reads only Vt[b] (1 MB).
    const int bid = blockIdx.x;
    const int b = bid & 7, rr = bid >> 3;   // rr 0..31
    const int jb2 = rr & 15, cc2 = rr >> 4;
    const int t = threadIdx.x, wave = t >> 6, lane = t & 63;
    const int wy = wave >> 2, wx = wave & 3, quad = lane >> 4, lr = lane & 15;
    const _Float16* Vtb = Vt + ((size_t)(b * 256 + cc2 * 128)) * 2048;
    floatx4 acc[4][2] = {};

    if (t < 128) {
        float s = 0.f;
#pragma unroll
        for (int p = 0; p < 16; ++p)
            s += Spart[((size_t)(b * 16 + p)) * 2048 + jb2 * 128 + t];
        invSl[t] = 1.0f / s;
    }

    // W-path thread mapping: 2 consecutive j x 8 consecutive i per thread
    const int j0 = (t & 63) * 2, ti = t >> 6;
    float* Wb = W + ((size_t)b * 2048) * 2048 + jb2 * 128;
    const bool dutyE = (cc2 == 0), dutyO = (cc2 == 1);

    half8v av0[2], bv0[2], av1[2], bv1[2];
    G2_LOAD(0, av0, bv0);
    G2_STAGE(As[0], Bs[0], av0, bv0);
    G2_LOAD(1, av1, bv1);
    __syncthreads();
    const float iv0 = invSl[j0], iv1 = invSl[j0 + 1];

    for (int ip = 0; ip < 16; ++ip) {
        const int itE = ip * 2, itO = ip * 2 + 1;
        // even step: buf0 current, regs set1 hold tile itE+1
        G2_STAGE(As[1], Bs[1], av1, bv1);
        G2_LOAD((itE + 2) & 31, av0, bv0);
        if (dutyE) G2_WDUTY(Bs[0], itE);
        G2_MFMA(As[0], Bs[0]);
        BAR_LGKM();
        // odd step: buf1 current, regs set0 hold tile itO+1
        G2_STAGE(As[0], Bs[0], av0, bv0);
        G2_LOAD((itO + 2) & 31, av1, bv1);
        if (dutyO) G2_WDUTY(Bs[1], itO);
        G2_MFMA(As[1], Bs[1]);
        BAR_LGKM();
    }

    float* Ob = Out + ((size_t)(b * 256 + cc2 * 128)) * 2048 + jb2 * 128;
    float iv[2];
#pragma unroll
    for (int n = 0; n < 2; ++n)
        iv[n] = invSl[wx * 32 + n * 16 + lr];
#pragma unroll
    for (int m = 0; m < 4; ++m) {
        const int c0r = wy * 64 + m * 16 + quad * 4;
#pragma unroll
        for (int n = 0; n < 2; ++n) {
            const int j = wx * 32 + n * 16 + lr;
#pragma unroll
            for (int r2 = 0; r2 < 4; ++r2)
                __builtin_nontemporal_store(acc[m][n][r2] * iv[n],
                                            &Ob[(size_t)(c0r + r2) * 2048 + j]);
        }
    }
}

extern "C" void kernel_launch(void* const* d_in, const int* in_sizes, int n_in,
                              void* d_out, int out_size, void* d_ws, size_t ws_size,
                              hipStream_t stream) {
    const float* q = (const float*)d_in[0];
    const float* k = (const float*)d_in[1];
    const float* v = (const float*)d_in[2];
    float* out = (float*)d_out;
    float* w = out + (size_t)BATCH * CDIM * NDIM;  // weights region

    char* ws = (char*)d_ws;
    float* Spart = (float*)(ws + WS_SPART);
    _Float16* Kt = (_Float16*)(ws + WS_KT);
    _Float16* Qt = (_Float16*)(ws + WS_QT);
    _Float16* Vt = (_Float16*)(ws + WS_VT);
    _Float16* EhT = (_Float16*)(ws + WS_EHT);

    prep_kernel<<<dim3(1024, 3), 256, 0, stream>>>(q, k, v, Kt, Qt, Vt);
    gemm1_kernel<<<2048, 256, 0, stream>>>(Kt, Qt, EhT, Spart);
    gemm2_kernel<<<256, 512, 0, stream>>>(Vt, EhT, Spart, w, out);
}